// Round 7
// baseline (132.303 us; speedup 1.0000x reference)
//
#include <hip/hip_runtime.h>

// GAT fused v7: 3 blocks/CU (50.5 KB LDS), alpha in registers (B-frag layout,
// softmax overlapped with GEMM1), sHt overlays sX, non-draining barriers,
// x reg-prefetch. VGPR budget ~130 < 168 cap (launch_bounds 256,3): no spills.

typedef __attribute__((ext_vector_type(8))) short short8;  // 8 bf16
typedef __attribute__((ext_vector_type(4))) float f32x4;

constexpr int   NTILES    = 8192;
constexpr int   GRID      = 768;      // 3 blocks/CU * 256 CUs
constexpr float NEG_SLOPE = 0.2f;
constexpr float LN_EPS    = 1e-5f;

__device__ __forceinline__ unsigned short f2bf(float f) {
    unsigned int u = __builtin_bit_cast(unsigned int, f);
    return (unsigned short)((u + 0x7FFFu + ((u >> 16) & 1u)) >> 16);
}
__device__ __forceinline__ unsigned pack2(float lo, float hi) {
    return (unsigned)f2bf(lo) | ((unsigned)f2bf(hi) << 16);
}
__device__ __forceinline__ unsigned swz256(int row, int bytecol) {
    return (unsigned)(row * 256 + bytecol) ^ (unsigned)((row & 7) << 4);
}
__device__ __forceinline__ unsigned swz128(int row, int bytecol) {
    return (unsigned)(row * 128 + bytecol) ^ (unsigned)((row & 7) << 4);
}

// Barrier without __syncthreads' vmcnt(0) drain: LDS ops complete (lgkmcnt),
// global loads/stores stay in flight across it (T4). Proven in v5/v6.
#define LBAR() do { asm volatile("s_waitcnt lgkmcnt(0)"); __builtin_amdgcn_s_barrier(); } while (0)

__launch_bounds__(256, 3)
__global__ void gat_mfma7(const float* __restrict__ x,
                          const float* __restrict__ W,
                          const float* __restrict__ a_src,
                          const float* __restrict__ a_dst,
                          const float* __restrict__ gamma,
                          const float* __restrict__ beta,
                          float* __restrict__ out)
{
    __shared__ __align__(16) unsigned short sWt[128 * 128]; // W^T bf16, swz256 (32 KB)
    __shared__ __align__(16) unsigned short sXH[64 * 128];  // x tile (swz256) THEN h^T (swz128), 16 KB
    __shared__ __align__(16) float s_src[64];
    __shared__ __align__(16) float s_dst[64];
    __shared__ __align__(16) float s_ws[128];
    __shared__ __align__(16) float s_wd[128];
    __shared__ __align__(16) float s_g[128];
    __shared__ __align__(16) float s_b[128];

    const int t    = threadIdx.x;
    const int lane = t & 63;
    const int w    = t >> 6;      // wave 0..3
    const int l15  = lane & 15;
    const int lg   = lane >> 4;   // 0..3

    // ---- one-time: ws = W@a_src, wd = W@a_dst ; gamma/beta ----
    if (t < 128) {
        const float4* W4  = reinterpret_cast<const float4*>(W) + t * 32;
        const float4* as4 = reinterpret_cast<const float4*>(a_src);
        const float4* ad4 = reinterpret_cast<const float4*>(a_dst);
        float ws = 0.f, wd = 0.f;
        for (int n4 = 0; n4 < 32; ++n4) {
            float4 wr = W4[n4], as = as4[n4], ad = ad4[n4];
            ws += wr.x*as.x + wr.y*as.y + wr.z*as.z + wr.w*as.w;
            wd += wr.x*ad.x + wr.y*ad.y + wr.z*ad.z + wr.w*ad.w;
        }
        s_ws[t] = ws; s_wd[t] = wd;
        s_g[t] = gamma[t]; s_b[t] = beta[t];
    }

    // ---- one-time: stage W^T as bf16 into LDS ----
    {
        const float4* W4 = reinterpret_cast<const float4*>(W);
        for (int c = 0; c < 16; ++c) {
            int idx4 = t + 256 * c;          // 0..4095
            float4 v = W4[idx4];
            int k  = idx4 >> 5;
            int n0 = (idx4 & 31) << 2;
            *(unsigned short*)((char*)sWt + swz256(n0 + 0, k * 2)) = f2bf(v.x);
            *(unsigned short*)((char*)sWt + swz256(n0 + 1, k * 2)) = f2bf(v.y);
            *(unsigned short*)((char*)sWt + swz256(n0 + 2, k * 2)) = f2bf(v.z);
            *(unsigned short*)((char*)sWt + swz256(n0 + 3, k * 2)) = f2bf(v.w);
        }
    }
    __syncthreads();

    // per-thread ws/wd slice to regs
    float wsr[8], wdr[8];
    {
        const int k0 = (t & 15) * 8;
        #pragma unroll
        for (int q = 0; q < 8; ++q) { wsr[q] = s_ws[k0 + q]; wdr[q] = s_wd[k0 + q]; }
    }

    // ---- prologue: first x tile into regs ----
    float4 px[8];
    {
        const float4* x4 = reinterpret_cast<const float4*>(x + (size_t)blockIdx.x * 8192);
        #pragma unroll
        for (int c = 0; c < 4; ++c) {
            const int idx8 = t + 256 * c;
            px[2*c]   = x4[idx8 * 2];
            px[2*c+1] = x4[idx8 * 2 + 1];
        }
    }

    for (int tile = blockIdx.x; tile < NTILES; tile += GRID) {
        float* ob = out + (size_t)tile * 8192;

        // ---- Phase A: stage x (bf16, swz256) + f32 scores from px regs ----
        #pragma unroll
        for (int c = 0; c < 4; ++c) {
            const float4 v0 = px[2*c], v1 = px[2*c+1];
            float ps = v0.x*wsr[0] + v0.y*wsr[1] + v0.z*wsr[2] + v0.w*wsr[3]
                     + v1.x*wsr[4] + v1.y*wsr[5] + v1.z*wsr[6] + v1.w*wsr[7];
            float pd = v0.x*wdr[0] + v0.y*wdr[1] + v0.z*wdr[2] + v0.w*wdr[3]
                     + v1.x*wdr[4] + v1.y*wdr[5] + v1.z*wdr[6] + v1.w*wdr[7];
            uint4 pk;
            pk.x = pack2(v0.x, v0.y); pk.y = pack2(v0.z, v0.w);
            pk.z = pack2(v1.x, v1.y); pk.w = pack2(v1.z, v1.w);
            const int m = (t >> 4) + 16 * c;
            *(uint4*)((char*)sXH + swz256(m, (t & 15) * 16)) = pk;
            #pragma unroll
            for (int msk = 1; msk < 16; msk <<= 1) {
                ps += __shfl_xor(ps, msk, 64);
                pd += __shfl_xor(pd, msk, 64);
            }
            if ((t & 15) == 0) { s_src[m] = ps; s_dst[m] = pd; }
        }

        // ---- prefetch next tile's x (stays in flight across LBARs) ----
        if (tile + GRID < NTILES) {
            const float4* xn = reinterpret_cast<const float4*>(x + (size_t)(tile + GRID) * 8192);
            #pragma unroll
            for (int c = 0; c < 4; ++c) {
                const int idx8 = t + 256 * c;
                px[2*c]   = xn[idx8 * 2];
                px[2*c+1] = xn[idx8 * 2 + 1];
            }
        }
        LBAR();   // S1: sXH(x) + scores visible

        // ---- Phase B: GEMM1 h = x@W (acc in regs) ∥ softmax -> alpha regs ----
        f32x4 acc[4][2];
        #pragma unroll
        for (int mi = 0; mi < 4; ++mi) {
            acc[mi][0] = f32x4{0.f,0.f,0.f,0.f};
            acc[mi][1] = f32x4{0.f,0.f,0.f,0.f};
        }
        #pragma unroll
        for (int kb = 0; kb < 4; ++kb) {
            const int kbyte = kb * 64 + lg * 16;
            short8 bfr0 = *(const short8*)((char*)sWt + swz256(32 * w +  0 + l15, kbyte));
            short8 bfr1 = *(const short8*)((char*)sWt + swz256(32 * w + 16 + l15, kbyte));
            #pragma unroll
            for (int mi = 0; mi < 4; ++mi) {
                short8 afr = *(const short8*)((char*)sXH + swz256(mi * 16 + l15, kbyte));
                acc[mi][0] = __builtin_amdgcn_mfma_f32_16x16x32_bf16(afr, bfr0, acc[mi][0], 0, 0, 0);
                acc[mi][1] = __builtin_amdgcn_mfma_f32_16x16x32_bf16(afr, bfr1, acc[mi][1], 0, 0, 0);
            }
        }

        // softmax for row i = w*16+l15, j-slices lg*8+q and 32+lg*8+q.
        // Row-reduce across lanes with same l15 (lg differs): shfl_xor 16,32.
        // Result = GEMM2 B-fragments, directly in registers.
        short8 pa0, pa1;
        {
            const float srci = s_src[w * 16 + l15];
            const float4 dA0 = *(const float4*)&s_dst[lg * 8];
            const float4 dA1 = *(const float4*)&s_dst[lg * 8 + 4];
            const float4 dB0 = *(const float4*)&s_dst[32 + lg * 8];
            const float4 dB1 = *(const float4*)&s_dst[32 + lg * 8 + 4];
            float e[16] = { srci+dA0.x, srci+dA0.y, srci+dA0.z, srci+dA0.w,
                            srci+dA1.x, srci+dA1.y, srci+dA1.z, srci+dA1.w,
                            srci+dB0.x, srci+dB0.y, srci+dB0.z, srci+dB0.w,
                            srci+dB1.x, srci+dB1.y, srci+dB1.z, srci+dB1.w };
            float mx = -1e30f;
            #pragma unroll
            for (int q = 0; q < 16; ++q) {
                e[q] = (e[q] >= 0.f) ? e[q] : NEG_SLOPE * e[q];
                mx = fmaxf(mx, e[q]);
            }
            mx = fmaxf(mx, __shfl_xor(mx, 16, 64));
            mx = fmaxf(mx, __shfl_xor(mx, 32, 64));
            float sm = 0.f;
            #pragma unroll
            for (int q = 0; q < 16; ++q) { e[q] = __expf(e[q] - mx); sm += e[q]; }
            sm += __shfl_xor(sm, 16, 64);
            sm += __shfl_xor(sm, 32, 64);
            const float inv = 1.0f / sm;
            uint4 p0, p1;
            p0.x = pack2(e[0]*inv,  e[1]*inv);  p0.y = pack2(e[2]*inv,  e[3]*inv);
            p0.z = pack2(e[4]*inv,  e[5]*inv);  p0.w = pack2(e[6]*inv,  e[7]*inv);
            p1.x = pack2(e[8]*inv,  e[9]*inv);  p1.y = pack2(e[10]*inv, e[11]*inv);
            p1.z = pack2(e[12]*inv, e[13]*inv); p1.w = pack2(e[14]*inv, e[15]*inv);
            pa0 = __builtin_bit_cast(short8, p0);
            pa1 = __builtin_bit_cast(short8, p1);
        }
        LBAR();   // S2: all waves done reading sXH as x

        // ---- write h^T (swz128) over sXH ----
        #pragma unroll
        for (int mi = 0; mi < 4; ++mi) {
            const int m0 = mi * 16 + lg * 4;
            #pragma unroll
            for (int nb = 0; nb < 2; ++nb) {
                const int n = 32 * w + nb * 16 + l15;
                uint2 pk;
                pk.x = pack2(acc[mi][nb][0], acc[mi][nb][1]);
                pk.y = pack2(acc[mi][nb][2], acc[mi][nb][3]);
                *(uint2*)((char*)sXH + swz128(n, m0 * 2)) = pk;
            }
        }
        LBAR();   // S3: h^T visible

        // ---- Phase D: GEMM2 out^T = h^T @ alpha^T (B = alpha regs) + LN + store ----
        f32x4 o[8];
        #pragma unroll
        for (int mi = 0; mi < 8; ++mi) o[mi] = f32x4{0.f,0.f,0.f,0.f};
        #pragma unroll
        for (int kb = 0; kb < 2; ++kb) {
            const int jbyte = kb * 64 + lg * 16;
            const short8 bfr = (kb == 0) ? pa0 : pa1;
            #pragma unroll
            for (int mi = 0; mi < 8; ++mi) {
                short8 afr = *(const short8*)((char*)sXH + swz128(mi * 16 + l15, jbyte));
                o[mi] = __builtin_amdgcn_mfma_f32_16x16x32_bf16(afr, bfr, o[mi], 0, 0, 0);
            }
        }

        float sm1 = 0.f, sm2 = 0.f;
        #pragma unroll
        for (int mi = 0; mi < 8; ++mi) {
            #pragma unroll
            for (int r = 0; r < 4; ++r) { const float v = o[mi][r]; sm1 += v; sm2 += v * v; }
        }
        sm1 += __shfl_xor(sm1, 16, 64); sm2 += __shfl_xor(sm2, 16, 64);
        sm1 += __shfl_xor(sm1, 32, 64); sm2 += __shfl_xor(sm2, 32, 64);
        const float mu   = sm1 * (1.f / 128.f);
        const float var  = sm2 * (1.f / 128.f) - mu * mu;
        const float rstd = rsqrtf(var + LN_EPS);

        float* orow = ob + (w * 16 + l15) * 128;
        #pragma unroll
        for (int mi = 0; mi < 8; ++mi) {
            const int n0 = mi * 16 + lg * 4;
            const float4 gv = *(const float4*)&s_g[n0];
            const float4 bv = *(const float4*)&s_b[n0];
            float4 vo;
            vo.x = fmaxf((o[mi][0] - mu) * rstd * gv.x + bv.x, 0.f);
            vo.y = fmaxf((o[mi][1] - mu) * rstd * gv.y + bv.y, 0.f);
            vo.z = fmaxf((o[mi][2] - mu) * rstd * gv.z + bv.z, 0.f);
            vo.w = fmaxf((o[mi][3] - mu) * rstd * gv.w + bv.w, 0.f);
            *(float4*)(orow + n0) = vo;
        }
        LBAR();   // S4: h^T reads done before next tile's staging overwrites sXH
    }
}

extern "C" void kernel_launch(void* const* d_in, const int* in_sizes, int n_in,
                              void* d_out, int out_size, void* d_ws, size_t ws_size,
                              hipStream_t stream) {
    const float* x   = (const float*)d_in[0];
    const float* W   = (const float*)d_in[1];
    const float* asv = (const float*)d_in[2];
    const float* adv = (const float*)d_in[3];
    const float* gm  = (const float*)d_in[4];
    const float* bt  = (const float*)d_in[5];
    float* out = (float*)d_out;

    hipLaunchKernelGGL(gat_mfma7, dim3(GRID), dim3(256), 0, stream,
                       x, W, asv, adv, gm, bt, out);
}